// Round 3
// baseline (178.118 us; speedup 1.0000x reference)
//
#include <hip/hip_runtime.h>
#include <stdint.h>

// Problem constants (from reference: B=2048, D=512, TAU=0.5)
#define DIM       512
#define NROWS     8192      // 4*B
#define HALF_ROWS 4096      // 2*B
#define TILE      128
#define BK        32
#define NTILE     64        // NROWS / TILE
#define NBLK      2080      // live upper-triangle tile pairs (finalize counter)

typedef float  floatx4 __attribute__((ext_vector_type(4)));
typedef __bf16 bf16x8  __attribute__((ext_vector_type(8)));

__device__ __forceinline__ void async_copy16(const unsigned short* g, unsigned short* l) {
    __builtin_amdgcn_global_load_lds(
        (const __attribute__((address_space(1))) uint32_t*)(g),
        (__attribute__((address_space(3))) uint32_t*)(l),
        16, 0, 0);
}

// L2-normalize rows of [emb_i; emb_j] -> bf16 rep[8192][512]; block 0 zeroes ws.
__global__ __launch_bounds__(256) void normalize_kernel(
    const float* __restrict__ emb_i, const float* __restrict__ emb_j,
    unsigned short* __restrict__ rep, double* __restrict__ ws)
{
    if (blockIdx.x == 0 && threadIdx.x == 0) {
        ws[0] = 0.0;
        ws[1] = 0.0;
        *(unsigned int*)((char*)ws + 16) = 0u;
    }
    const int wave = threadIdx.x >> 6;
    const int lane = threadIdx.x & 63;
    const int row  = blockIdx.x * 4 + wave;
    const float* src = (row < HALF_ROWS) ? (emb_i + (size_t)row * DIM)
                                         : (emb_j + (size_t)(row - HALF_ROWS) * DIM);
    const int c = lane * 8;
    float4 v0 = *(const float4*)(src + c);
    float4 v1 = *(const float4*)(src + c + 4);
    float s = v0.x*v0.x + v0.y*v0.y + v0.z*v0.z + v0.w*v0.w
            + v1.x*v1.x + v1.y*v1.y + v1.z*v1.z + v1.w*v1.w;
    #pragma unroll
    for (int off = 32; off; off >>= 1) s += __shfl_xor(s, off, 64);
    const float nrm = sqrtf(s);
    const float inv = 1.0f / fmaxf(nrm, 1e-12f);
    float f[8] = {v0.x*inv, v0.y*inv, v0.z*inv, v0.w*inv,
                  v1.x*inv, v1.y*inv, v1.z*inv, v1.w*inv};
    union { unsigned short h[8]; uint4 u; } pk;
    #pragma unroll
    for (int t = 0; t < 8; ++t) {   // fp32 -> bf16 round-to-nearest-even
        uint32_t b = __float_as_uint(f[t]);
        b += 0x7FFFu + ((b >> 16) & 1u);
        pk.h[t] = (unsigned short)(b >> 16);
    }
    *(uint4*)(rep + (size_t)row * DIM + c) = pk.u;
}

__device__ __forceinline__ void stage_pair(
    const unsigned short* __restrict__ rep, int i0, int j0, int k0,
    unsigned short* As, unsigned short* Bs,
    int p0, int r0, int jj0, int p1, int r1, int jj1)
{
    async_copy16(rep + (size_t)(i0 + r0) * DIM + k0 + jj0, As + p0 * 8);
    async_copy16(rep + (size_t)(j0 + r0) * DIM + k0 + jj0, Bs + p0 * 8);
    async_copy16(rep + (size_t)(i0 + r1) * DIM + k0 + jj1, As + p1 * 8);
    async_copy16(rep + (size_t)(j0 + r1) * DIM + k0 + jj1, Bs + p1 * 8);
}

__device__ __forceinline__ void compute_phase(
    const unsigned short* As, const unsigned short* Bs,
    int wm, int wn, int m, int sw, floatx4 acc[4][4])
{
    bf16x8 af[4], bfr[4];
    #pragma unroll
    for (int mt = 0; mt < 4; ++mt)
        af[mt] = *(const bf16x8*)(As + (wm * 64 + mt * 16 + m) * BK + sw);
    #pragma unroll
    for (int nt = 0; nt < 4; ++nt)
        bfr[nt] = *(const bf16x8*)(Bs + (wn * 64 + nt * 16 + m) * BK + sw);
    #pragma unroll
    for (int mt = 0; mt < 4; ++mt)
        #pragma unroll
        for (int nt = 0; nt < 4; ++nt)
            acc[mt][nt] = __builtin_amdgcn_mfma_f32_16x16x32_bf16(
                af[mt], bfr[nt], acc[mt][nt], 0, 0, 0);
}

// Fused Gram-tile + exp + reduction over upper-triangle tile pairs.
// Grid: 36 supertiles (8x8 tiles each) x 64 blocks. Per-XCD working set:
// 8 A-tiles + 1 B-tile = 1.1 MB << 4 MB L2. Double-buffered LDS with DMA
// prefetch issued right after each barrier (1-deep software pipeline; every
// barrier's vmcnt(0) drain is mandatory, overlapped by a full compute phase).
// LDS chunk swizzle keeps ds_read_b128 conflict-free. Last live block
// computes the loss (fused finalize).
__global__ __launch_bounds__(256) void gram_kernel(
    const unsigned short* __restrict__ rep, double* __restrict__ ws,
    float* __restrict__ out)
{
    // supertile decode: 8x8 supertile upper triangle, row-major
    int s = blockIdx.x >> 6;
    int Bi = 0, rem = s;
    while (rem >= 8 - Bi) { rem -= 8 - Bi; ++Bi; }
    const int Bj = Bi + rem;
    const int t = blockIdx.x & 63;
    const int bi = Bi * 8 + (t >> 3);
    const int bj = Bj * 8 + (t & 7);
    if (bi > bj) return;   // dead only inside diagonal supertiles

    __shared__ unsigned short As0[TILE * BK], Bs0[TILE * BK];  // 8 KB each
    __shared__ unsigned short As1[TILE * BK], Bs1[TILE * BK];
    __shared__ float red[8];

    const int tid  = threadIdx.x;
    const int wave = tid >> 6, lane = tid & 63;
    const int wm = wave >> 1, wn = wave & 1;   // 2x2 waves of 64x64 quadrants
    const int m = lane & 15, quad = lane >> 4; // MFMA fragment coords
    const int sw = (quad ^ ((m >> 1) & 3)) * 8; // swizzled k-chunk offset

    floatx4 acc[4][4];
    #pragma unroll
    for (int a = 0; a < 4; ++a)
        #pragma unroll
        for (int b = 0; b < 4; ++b)
            #pragma unroll
            for (int e = 0; e < 4; ++e) acc[a][b][e] = 0.0f;

    const int i0 = bi * TILE, j0 = bj * TILE;

    // staging decode (hoisted): this thread's two physical slots per array
    const int p0 = tid,       r0 = p0 >> 2, jj0 = ((p0 & 3) ^ ((r0 >> 1) & 3)) * 8;
    const int p1 = 256 + tid, r1 = p1 >> 2, jj1 = ((p1 & 3) ^ ((r1 >> 1) & 3)) * 8;

    stage_pair(rep, i0, j0, 0, As0, Bs0, p0, r0, jj0, p1, r1, jj1);

    for (int k0 = 0; k0 < DIM; k0 += 2 * BK) {
        __syncthreads();   // drains own buf0 DMAs (issued 1 phase ago) + rendezvous
        if (k0 + BK < DIM)
            stage_pair(rep, i0, j0, k0 + BK, As1, Bs1, p0, r0, jj0, p1, r1, jj1);
        compute_phase(As0, Bs0, wm, wn, m, sw, acc);
        __syncthreads();   // drains buf1 DMAs, overlapped by the phase above
        if (k0 + 2 * BK < DIM)
            stage_pair(rep, i0, j0, k0 + 2 * BK, As0, Bs0, p0, r0, jj0, p1, r1, jj1);
        compute_phase(As1, Bs1, wm, wn, m, sw, acc);
    }

    // Epilogue: exp(sim/tau) = exp2(sim * 2/ln2); accumulate total + band sums.
    float s_all = 0.0f, s_pos = 0.0f;
    const float LOG2E2 = 2.885390081777927f;  // 2 / ln(2)
    #pragma unroll
    for (int mt = 0; mt < 4; ++mt) {
        const int ibase = i0 + wm * 64 + mt * 16 + quad * 4;
        #pragma unroll
        for (int nt = 0; nt < 4; ++nt) {
            const int j = j0 + wn * 64 + nt * 16 + m;
            const floatx4 a = acc[mt][nt];
            #pragma unroll
            for (int r2 = 0; r2 < 4; ++r2) {
                const int i = ibase + r2;
                const float e = exp2f(a[r2] * LOG2E2);
                if (i != j) s_all += e;
                const int d = j - i;  // upper triangle: band offsets positive
                if (d == 2048 || d == 4096 || d == 6144) s_pos += e;
            }
        }
    }
    #pragma unroll
    for (int off = 32; off; off >>= 1) {
        s_all += __shfl_xor(s_all, off, 64);
        s_pos += __shfl_xor(s_pos, off, 64);
    }
    if (lane == 0) { red[wave] = s_all; red[4 + wave] = s_pos; }
    __syncthreads();
    if (tid == 0) {
        const float w  = (bi == bj) ? 1.0f : 2.0f;
        const float ta = (red[0] + red[1] + red[2] + red[3]) * w;
        const float tp = (red[4] + red[5] + red[6] + red[7]) * w;
        atomicAdd(&ws[0], (double)ta);
        atomicAdd(&ws[1], (double)tp);
        __threadfence();
        unsigned int* cnt = (unsigned int*)((char*)ws + 16);
        const unsigned int prev = atomicAdd(cnt, 1u);
        if (prev == NBLK - 1) {                 // last live block: fused finalize
            __threadfence();
            const double tot = atomicAdd(&ws[0], 0.0);  // coherent readback
            const double nom = atomicAdd(&ws[1], 0.0);
            const double den = tot - nom;
            out[0] = (float)(-log(nom / den) / (double)NROWS);
        }
    }
}

extern "C" void kernel_launch(void* const* d_in, const int* in_sizes, int n_in,
                              void* d_out, int out_size, void* d_ws, size_t ws_size,
                              hipStream_t stream) {
    const float* emb_i = (const float*)d_in[0];
    const float* emb_j = (const float*)d_in[1];
    float* out = (float*)d_out;
    double* ws = (double*)d_ws;                                   // accumulators + counter
    unsigned short* rep = (unsigned short*)((char*)d_ws + 256);   // bf16 [8192][512]

    hipLaunchKernelGGL(normalize_kernel, dim3(NROWS / 4), dim3(256), 0, stream,
                       emb_i, emb_j, rep, ws);
    hipLaunchKernelGGL(gram_kernel, dim3(36 * 64), dim3(256), 0, stream, rep, ws, out);
}

// Round 4
// 163.248 us; speedup vs baseline: 1.0911x; 1.0911x over previous
//
#include <hip/hip_runtime.h>
#include <stdint.h>

// Problem constants (from reference: B=2048, D=512, TAU=0.5)
#define DIM       512
#define NROWS     8192      // 4*B
#define HALF_ROWS 4096      // 2*B
#define TILE      128
#define BKP       64        // K-cols staged per phase
#define NTILE     64        // NROWS / TILE
#define NBLK      2080      // live upper-triangle tile pairs (finalize counter)

typedef float  floatx4 __attribute__((ext_vector_type(4)));
typedef __bf16 bf16x8  __attribute__((ext_vector_type(8)));

__device__ __forceinline__ void async_copy16(const unsigned short* g, unsigned short* l) {
    __builtin_amdgcn_global_load_lds(
        (const __attribute__((address_space(1))) uint32_t*)(g),
        (__attribute__((address_space(3))) uint32_t*)(l),
        16, 0, 0);
}

// L2-normalize rows of [emb_i; emb_j] -> bf16 rep[8192][512]; block 0 zeroes ws.
// (ws init here is visible to the next kernel via dispatch-boundary coherence.)
__global__ __launch_bounds__(256) void normalize_kernel(
    const float* __restrict__ emb_i, const float* __restrict__ emb_j,
    unsigned short* __restrict__ rep, double* __restrict__ ws)
{
    if (blockIdx.x == 0 && threadIdx.x == 0) {
        ws[0] = 0.0;
        ws[1] = 0.0;
        *(unsigned int*)((char*)ws + 16) = 0u;
    }
    const int wave = threadIdx.x >> 6;
    const int lane = threadIdx.x & 63;
    const int row  = blockIdx.x * 4 + wave;
    const float* src = (row < HALF_ROWS) ? (emb_i + (size_t)row * DIM)
                                         : (emb_j + (size_t)(row - HALF_ROWS) * DIM);
    const int c = lane * 8;
    float4 v0 = *(const float4*)(src + c);
    float4 v1 = *(const float4*)(src + c + 4);
    float s = v0.x*v0.x + v0.y*v0.y + v0.z*v0.z + v0.w*v0.w
            + v1.x*v1.x + v1.y*v1.y + v1.z*v1.z + v1.w*v1.w;
    #pragma unroll
    for (int off = 32; off; off >>= 1) s += __shfl_xor(s, off, 64);
    const float nrm = sqrtf(s);
    const float inv = 1.0f / fmaxf(nrm, 1e-12f);
    float f[8] = {v0.x*inv, v0.y*inv, v0.z*inv, v0.w*inv,
                  v1.x*inv, v1.y*inv, v1.z*inv, v1.w*inv};
    union { unsigned short h[8]; uint4 u; } pk;
    #pragma unroll
    for (int t = 0; t < 8; ++t) {   // fp32 -> bf16 round-to-nearest-even
        uint32_t b = __float_as_uint(f[t]);
        b += 0x7FFFu + ((b >> 16) & 1u);
        pk.h[t] = (unsigned short)(b >> 16);
    }
    *(uint4*)(rep + (size_t)row * DIM + c) = pk.u;
}

// Fused Gram-tile + exp + reduction over upper-triangle tile pairs.
// Grid: 36 supertiles (8x8 tiles) x 64 blocks -> per-XCD working set ~1.1 MB.
// BK=64 single-buffered LDS (32 KB): 8 phases, 2 barriers each.
// LDS chunk swizzle: 16B chunk c of row r stored at slot r*8 + (c ^ (r&7))
// -> both the DMA staging (lane-contiguous LDS dest) and ds_read_b128
// fragment reads are bank-conflict-free.
// NO __threadfence (it invalidates the whole per-XCD L2 -- the round-2/3
// regression). Atomic ordering via data dependency on atomicAdd returns.
__global__ __launch_bounds__(256) void gram_kernel(
    const unsigned short* __restrict__ rep, double* __restrict__ ws,
    float* __restrict__ out)
{
    // supertile decode: 8x8 supertile upper triangle, row-major
    int s = blockIdx.x >> 6;
    int Bi = 0, rem = s;
    while (rem >= 8 - Bi) { rem -= 8 - Bi; ++Bi; }
    const int Bj = Bi + rem;
    const int t = blockIdx.x & 63;
    const int bi = Bi * 8 + (t >> 3);
    const int bj = Bj * 8 + (t & 7);
    if (bi > bj) return;   // dead only inside diagonal supertiles

    __shared__ unsigned short As[TILE * BKP];  // 16 KB, swizzled [128][8 chunks]
    __shared__ unsigned short Bs[TILE * BKP];  // 16 KB
    __shared__ float red[8];

    const int tid  = threadIdx.x;
    const int wave = tid >> 6, lane = tid & 63;
    const int wm = wave >> 1, wn = wave & 1;   // 2x2 waves of 64x64 quadrants
    const int m = lane & 15, quad = lane >> 4; // MFMA fragment coords
    // swizzled fragment read offsets (shorts) for the two 32-col k-subphases
    const int sw0 = ((quad)     ^ (m & 7)) * 8;
    const int sw1 = ((4 + quad) ^ (m & 7)) * 8;

    floatx4 acc[4][4];
    #pragma unroll
    for (int a = 0; a < 4; ++a)
        #pragma unroll
        for (int b = 0; b < 4; ++b)
            #pragma unroll
            for (int e = 0; e < 4; ++e) acc[a][b][e] = 0.0f;

    const int i0 = bi * TILE, j0 = bj * TILE;

    // staging decode (hoisted): 4 physical 16B slots per thread per tile.
    // slot p -> row r = p>>3, physical chunk p&7, logical chunk (p&7)^(r&7)
    int rr[4], jj[4];
    #pragma unroll
    for (int q = 0; q < 4; ++q) {
        const int p = q * 256 + tid;
        rr[q] = p >> 3;
        jj[q] = ((p & 7) ^ (rr[q] & 7)) * 8;
    }

    for (int k0 = 0; k0 < DIM; k0 += BKP) {
        #pragma unroll
        for (int q = 0; q < 4; ++q) {
            const int p = q * 256 + tid;
            async_copy16(rep + (size_t)(i0 + rr[q]) * DIM + k0 + jj[q], As + p * 8);
            async_copy16(rep + (size_t)(j0 + rr[q]) * DIM + k0 + jj[q], Bs + p * 8);
        }
        __syncthreads();   // drain own DMAs + rendezvous

        #pragma unroll
        for (int kk = 0; kk < 2; ++kk) {
            const int sw = kk ? sw1 : sw0;
            bf16x8 af[4], bfr[4];
            #pragma unroll
            for (int mt = 0; mt < 4; ++mt)
                af[mt] = *(const bf16x8*)(As + (wm * 64 + mt * 16 + m) * BKP + sw);
            #pragma unroll
            for (int nt = 0; nt < 4; ++nt)
                bfr[nt] = *(const bf16x8*)(Bs + (wn * 64 + nt * 16 + m) * BKP + sw);
            #pragma unroll
            for (int mt = 0; mt < 4; ++mt)
                #pragma unroll
                for (int nt = 0; nt < 4; ++nt)
                    acc[mt][nt] = __builtin_amdgcn_mfma_f32_16x16x32_bf16(
                        af[mt], bfr[nt], acc[mt][nt], 0, 0, 0);
        }
        __syncthreads();   // protect LDS before next phase overwrites
    }

    // Epilogue: exp(sim/tau) = exp2(sim * 2/ln2); accumulate total + band sums.
    float s_all = 0.0f, s_pos = 0.0f;
    const float LOG2E2 = 2.885390081777927f;  // 2 / ln(2)
    #pragma unroll
    for (int mt = 0; mt < 4; ++mt) {
        const int ibase = i0 + wm * 64 + mt * 16 + quad * 4;
        #pragma unroll
        for (int nt = 0; nt < 4; ++nt) {
            const int j = j0 + wn * 64 + nt * 16 + m;
            const floatx4 a = acc[mt][nt];
            #pragma unroll
            for (int r2 = 0; r2 < 4; ++r2) {
                const int i = ibase + r2;
                const float e = exp2f(a[r2] * LOG2E2);
                if (i != j) s_all += e;
                const int d = j - i;  // upper triangle: band offsets positive
                if (d == 2048 || d == 4096 || d == 6144) s_pos += e;
            }
        }
    }
    #pragma unroll
    for (int off = 32; off; off >>= 1) {
        s_all += __shfl_xor(s_all, off, 64);
        s_pos += __shfl_xor(s_pos, off, 64);
    }
    if (lane == 0) { red[wave] = s_all; red[4 + wave] = s_pos; }
    __syncthreads();
    if (tid == 0) {
        const float w  = (bi == bj) ? 1.0f : 2.0f;
        const double ta = (double)((red[0] + red[1] + red[2] + red[3]) * w);
        const double tp = (double)((red[4] + red[5] + red[6] + red[7]) * w);
        // Device-scope atomics RMW at the coherent point. Order the counter
        // increment AFTER the sum-adds via a data dependency on their return
        // values (forces the vmcnt wait) -- no cache-invalidating fence.
        const double r0 = atomicAdd(&ws[0], ta);
        const double r1 = atomicAdd(&ws[1], tp);
        // sums are always >= 0, so both sign bits are 0 -> dep == 0 at runtime,
        // but the compiler cannot fold it away.
        const unsigned dep =
            (unsigned)(((unsigned long long)__double_as_longlong(r0) >> 63) &
                       ((unsigned long long)__double_as_longlong(r1) >> 63));
        unsigned int* cnt = (unsigned int*)((char*)ws + 16);
        const unsigned int prev = atomicAdd(cnt, 1u + dep);
        if (prev == NBLK - 1) {                 // last live block: fused finalize
            const double tot = atomicAdd(&ws[0], 0.0);  // coherent readback
            const double nom = atomicAdd(&ws[1], 0.0);
            const double den = tot - nom;
            out[0] = (float)(-log(nom / den) / (double)NROWS);
        }
    }
}

extern "C" void kernel_launch(void* const* d_in, const int* in_sizes, int n_in,
                              void* d_out, int out_size, void* d_ws, size_t ws_size,
                              hipStream_t stream) {
    const float* emb_i = (const float*)d_in[0];
    const float* emb_j = (const float*)d_in[1];
    float* out = (float*)d_out;
    double* ws = (double*)d_ws;                                   // accumulators + counter
    unsigned short* rep = (unsigned short*)((char*)d_ws + 256);   // bf16 [8192][512]

    hipLaunchKernelGGL(normalize_kernel, dim3(NROWS / 4), dim3(256), 0, stream,
                       emb_i, emb_j, rep, ws);
    hipLaunchKernelGGL(gram_kernel, dim3(36 * 64), dim3(256), 0, stream, rep, ws, out);
}